// Round 7
// baseline (141.655 us; speedup 1.0000x reference)
//
#include <hip/hip_runtime.h>
#include <hip/hip_bf16.h>
#include <math.h>

#define B_    4
#define T_    4096
#define E_    768
#define H_    6
#define D_    64
#define HD_   384
#define G_    1024
#define RATIO_ 4
#define TOPK_ 8
#define MT_   (B_*T_)   // 16384 rows total

typedef __attribute__((ext_vector_type(8))) short short8;
typedef __attribute__((ext_vector_type(4))) float f32x4;
typedef __hip_bfloat16 bf16;

// async global->LDS, 16B per lane (dest = linear tid*16; swizzle lives in the
// per-lane GLOBAL source address — rule #21: linear dest + inverse-swz source)
#define GLD16(g, l) __builtin_amdgcn_global_load_lds( \
    (const __attribute__((address_space(1))) void*)(g), \
    (__attribute__((address_space(3))) void*)(l), 16, 0, 0)

static __device__ __forceinline__ unsigned short f2bf(float f) {
  bf16 h = __float2bfloat16(f);
  return __builtin_bit_cast(unsigned short, h);
}

// ---------------------------------------------------------------------------
// transpose+convert weights: w [768][384] f32 -> wT [384][768] bf16 (x3)
// ---------------------------------------------------------------------------
__global__ __launch_bounds__(256) void cvt_w_t(
    const float* __restrict__ wq, const float* __restrict__ wk,
    const float* __restrict__ wg, bf16* __restrict__ outbase)
{
  const float* src = blockIdx.z == 0 ? wq : (blockIdx.z == 1 ? wk : wg);
  bf16* dst = outbase + (size_t)blockIdx.z * HD_ * E_;
  __shared__ float t[32][33];
  int r = threadIdx.x >> 5, c = threadIdx.x & 31;
  int k0 = blockIdx.x * 32, n0 = blockIdx.y * 32;
#pragma unroll
  for (int i = 0; i < 4; ++i)
    t[r + i * 8][c] = src[(size_t)(k0 + r + i * 8) * HD_ + n0 + c];
  __syncthreads();
#pragma unroll
  for (int i = 0; i < 4; ++i)
    dst[(size_t)(n0 + r + i * 8) * E_ + k0 + c] = __float2bfloat16(t[c][r + i * 8]);
}

// ---------------------------------------------------------------------------
// Fused q/k/gate projection from x (f32, converted in-register):
//   q  (rmsnormed)  bf16 [MT][384]
//   keys (softmax-pooled + rmsnormed) bf16 [B*G][384]
// 64x128 tile, BK=32. A: DIRECT global->reg (coalesced 16rows x 64B).
// B (3 mats): dbuf LDS 48KB -> 3 blocks/CU. Swizzled slots (conflict-free).
// ---------------------------------------------------------------------------
__global__ __launch_bounds__(256, 3) void gemm_qkg_mfma(
    const float* __restrict__ Xf, const bf16* __restrict__ WqT,
    const bf16* __restrict__ WkT, const bf16* __restrict__ WgT,
    const float* __restrict__ ape, bf16* __restrict__ Q,
    bf16* __restrict__ keys)
{
  // per buf (elems): Q0[0) Q1[2048) K0[4096) K1[6144) G0[8192) G1[10240)
  __shared__ bf16 lds[2][12288];   // 24KB/buf, 48KB total
  const int tid = threadIdx.x;
  const int lane = tid & 63, wv = tid >> 6;
  const int wm = wv >> 1, wn = wv & 1;
  const int ll = lane & 15, lh = lane >> 4;
  const int m0 = blockIdx.x * 64, n0 = blockIdx.y * 128;
  const int srow = tid >> 2;
  const int scol = (((tid & 3) ^ ((tid >> 3) & 3)) << 3);  // swizzled source slot
  const bf16* pQ0 = WqT + (size_t)(n0 + srow) * E_ + scol;
  const bf16* pQ1 = WqT + (size_t)(n0 + 64 + srow) * E_ + scol;
  const bf16* pK0 = WkT + (size_t)(n0 + srow) * E_ + scol;
  const bf16* pK1 = WkT + (size_t)(n0 + 64 + srow) * E_ + scol;
  const bf16* pG0 = WgT + (size_t)(n0 + srow) * E_ + scol;
  const bf16* pG1 = WgT + (size_t)(n0 + 64 + srow) * E_ + scol;
  // A direct-from-global (f32): wave reads 16 rows x 64B contiguous per load
  const float* pA0 = Xf + (size_t)(m0 + wm * 32 + ll) * E_ + lh * 8;
  const float* pA1 = pA0 + (size_t)16 * E_;

#define QKG_STAGE(b, k0) do { \
    char* base_ = (char*)&lds[b][0] + tid * 16; \
    GLD16(pQ0 + (k0), base_); \
    GLD16(pQ1 + (k0), base_ + 4096); \
    GLD16(pK0 + (k0), base_ + 8192); \
    GLD16(pK1 + (k0), base_ + 12288); \
    GLD16(pG0 + (k0), base_ + 16384); \
    GLD16(pG1 + (k0), base_ + 20480); \
  } while (0)

  f32x4 accQ[2][4], accK[2][4], accG[2][4];
#pragma unroll
  for (int m = 0; m < 2; ++m)
#pragma unroll
    for (int n = 0; n < 4; ++n) {
      accQ[m][n] = (f32x4){0.f, 0.f, 0.f, 0.f};
      accK[m][n] = (f32x4){0.f, 0.f, 0.f, 0.f};
      accG[m][n] = (f32x4){0.f, 0.f, 0.f, 0.f};
    }
  const int asw = (lh ^ ((ll >> 1) & 3)) << 3;  // swizzled read slot (elems)

  QKG_STAGE(0, 0);
  __syncthreads();
  for (int k0 = 0; k0 < E_; k0 += 32) {
    const int cur = (k0 >> 5) & 1;
    if (k0 + 32 < E_) QKG_STAGE(cur ^ 1, k0 + 32);
    // A: f32 loads (independent of LDS; compiler schedules early), cvt in-reg
    float4 f00 = *reinterpret_cast<const float4*>(pA0 + k0);
    float4 f01 = *reinterpret_cast<const float4*>(pA0 + k0 + 4);
    float4 f10 = *reinterpret_cast<const float4*>(pA1 + k0);
    float4 f11 = *reinterpret_cast<const float4*>(pA1 + k0 + 4);
    const bf16* Lb = &lds[cur][0];
    short8 a[2], bq[4], bk[4], bg[4];
    {
      union { unsigned short u[8]; short8 v; } r0, r1;
      r0.u[0] = f2bf(f00.x); r0.u[1] = f2bf(f00.y); r0.u[2] = f2bf(f00.z); r0.u[3] = f2bf(f00.w);
      r0.u[4] = f2bf(f01.x); r0.u[5] = f2bf(f01.y); r0.u[6] = f2bf(f01.z); r0.u[7] = f2bf(f01.w);
      r1.u[0] = f2bf(f10.x); r1.u[1] = f2bf(f10.y); r1.u[2] = f2bf(f10.z); r1.u[3] = f2bf(f10.w);
      r1.u[4] = f2bf(f11.x); r1.u[5] = f2bf(f11.y); r1.u[6] = f2bf(f11.z); r1.u[7] = f2bf(f11.w);
      a[0] = r0.v; a[1] = r1.v;
    }
#pragma unroll
    for (int n = 0; n < 4; ++n) {
      int R = (wn * 64 + n * 16 + ll) * 32 + asw;
      bq[n] = *reinterpret_cast<const short8*>(&Lb[R]);
      bk[n] = *reinterpret_cast<const short8*>(&Lb[4096 + R]);
      bg[n] = *reinterpret_cast<const short8*>(&Lb[8192 + R]);
    }
#pragma unroll
    for (int m = 0; m < 2; ++m)
#pragma unroll
      for (int n = 0; n < 4; ++n) {
        accQ[m][n] = __builtin_amdgcn_mfma_f32_16x16x32_bf16(a[m], bq[n], accQ[m][n], 0, 0, 0);
        accK[m][n] = __builtin_amdgcn_mfma_f32_16x16x32_bf16(a[m], bk[n], accK[m][n], 0, 0, 0);
        accG[m][n] = __builtin_amdgcn_mfma_f32_16x16x32_bf16(a[m], bg[n], accG[m][n], 0, 0, 0);
      }
    __syncthreads();
  }
#undef QKG_STAGE

  // ---- q epilogue: per-(row,head) rmsnorm (wave's 64 cols == one head) ----
#pragma unroll
  for (int m = 0; m < 2; ++m)
#pragma unroll
    for (int j = 0; j < 4; ++j) {
      float ss = 0.f;
#pragma unroll
      for (int n = 0; n < 4; ++n) ss += accQ[m][n][j] * accQ[m][n][j];
      ss += __shfl_xor(ss, 1, 64); ss += __shfl_xor(ss, 2, 64);
      ss += __shfl_xor(ss, 4, 64); ss += __shfl_xor(ss, 8, 64);
      float scl = rsqrtf(ss * (1.0f / D_) + 1e-6f);
      int row = m0 + wm * 32 + m * 16 + lh * 4 + j;
#pragma unroll
      for (int n = 0; n < 4; ++n)
        Q[(size_t)row * HD_ + n0 + wn * 64 + n * 16 + ll] =
            __float2bfloat16(accQ[m][n][j] * scl);
    }

  // ---- keys epilogue: lane-local softmax over 4 group rows + rmsnorm ----
  float apev[4][4];
#pragma unroll
  for (int n = 0; n < 4; ++n) {
    int col = n0 + wn * 64 + n * 16 + ll;
#pragma unroll
    for (int j = 0; j < 4; ++j) apev[n][j] = ape[j * HD_ + col];
  }
#pragma unroll
  for (int m = 0; m < 2; ++m) {
    float pooled[4];
#pragma unroll
    for (int n = 0; n < 4; ++n) {
      float g0 = accG[m][n][0] + apev[n][0], g1 = accG[m][n][1] + apev[n][1];
      float g2 = accG[m][n][2] + apev[n][2], g3 = accG[m][n][3] + apev[n][3];
      float mx = fmaxf(fmaxf(g0, g1), fmaxf(g2, g3));
      float e0 = expf(g0 - mx), e1 = expf(g1 - mx);
      float e2 = expf(g2 - mx), e3 = expf(g3 - mx);
      float inv = 1.0f / (e0 + e1 + e2 + e3);
      pooled[n] = (accK[m][n][0] * e0 + accK[m][n][1] * e1 +
                   accK[m][n][2] * e2 + accK[m][n][3] * e3) * inv;
    }
    float ss = pooled[0] * pooled[0] + pooled[1] * pooled[1] +
               pooled[2] * pooled[2] + pooled[3] * pooled[3];
    ss += __shfl_xor(ss, 1, 64); ss += __shfl_xor(ss, 2, 64);
    ss += __shfl_xor(ss, 4, 64); ss += __shfl_xor(ss, 8, 64);
    float scl = rsqrtf(ss * (1.0f / D_) + 1e-6f);
    int prow = (m0 >> 2) + wm * 8 + m * 4 + lh;
#pragma unroll
    for (int n = 0; n < 4; ++n)
      keys[(size_t)prow * HD_ + n0 + wn * 64 + n * 16 + ll] =
          __float2bfloat16(pooled[n] * scl);
  }
}

// ---------------------------------------------------------------------------
// Batched score GEMM: scores[z] = q[z] @ keys[z]^T * (D^-0.5/H).
// A (q) direct global->reg; B (keys) dbuf LDS 16KB; causal dead-tile skip.
// ---------------------------------------------------------------------------
__global__ __launch_bounds__(256, 4) void gemm_score_mfma(
    const bf16* __restrict__ Qall, const bf16* __restrict__ Kall,
    float* __restrict__ Call)
{
  const int m0 = blockIdx.x * 64, n0 = blockIdx.y * 128;
  if (4 * n0 >= m0 + 64) return;   // all cols >= gmax for every row in tile
  __shared__ bf16 lds[2][4096];    // B only: 8KB/buf
  const bf16* Qb = Qall + (size_t)blockIdx.z * T_ * HD_;
  const bf16* Kb = Kall + (size_t)blockIdx.z * G_ * HD_;
  float* C = Call + (size_t)blockIdx.z * T_ * G_;
  const int tid = threadIdx.x;
  const int lane = tid & 63, wv = tid >> 6;
  const int wm = wv >> 1, wn = wv & 1;
  const int ll = lane & 15, lh = lane >> 4;
  const int srow = tid >> 2;
  const int scol = (((tid & 3) ^ ((tid >> 3) & 3)) << 3);
  const bf16* pB0 = Kb + (size_t)(n0 + srow) * HD_ + scol;
  const bf16* pB1 = Kb + (size_t)(n0 + 64 + srow) * HD_ + scol;
  const bf16* pA0 = Qb + (size_t)(m0 + wm * 32 + ll) * HD_ + lh * 8;
  const bf16* pA1 = pA0 + (size_t)16 * HD_;

#define S_STAGE(b, k0) do { \
    char* base_ = (char*)&lds[b][0] + tid * 16; \
    GLD16(pB0 + (k0), base_); \
    GLD16(pB1 + (k0), base_ + 4096); \
  } while (0)

  f32x4 acc[2][4];
#pragma unroll
  for (int m = 0; m < 2; ++m)
#pragma unroll
    for (int n = 0; n < 4; ++n) acc[m][n] = (f32x4){0.f, 0.f, 0.f, 0.f};
  const int asw = (lh ^ ((ll >> 1) & 3)) << 3;

  S_STAGE(0, 0);
  __syncthreads();
  for (int k0 = 0; k0 < HD_; k0 += 32) {
    const int cur = (k0 >> 5) & 1;
    if (k0 + 32 < HD_) S_STAGE(cur ^ 1, k0 + 32);
    short8 a[2], b[4];
    a[0] = *reinterpret_cast<const short8*>(pA0 + k0);
    a[1] = *reinterpret_cast<const short8*>(pA1 + k0);
    const bf16* Lb = &lds[cur][0];
#pragma unroll
    for (int n = 0; n < 4; ++n)
      b[n] = *reinterpret_cast<const short8*>(&Lb[(wn * 64 + n * 16 + ll) * 32 + asw]);
#pragma unroll
    for (int m = 0; m < 2; ++m)
#pragma unroll
      for (int n = 0; n < 4; ++n)
        acc[m][n] = __builtin_amdgcn_mfma_f32_16x16x32_bf16(a[m], b[n], acc[m][n], 0, 0, 0);
    __syncthreads();
  }
#undef S_STAGE
  const float scale = 0.125f / 6.0f;
#pragma unroll
  for (int m = 0; m < 2; ++m)
#pragma unroll
    for (int j = 0; j < 4; ++j) {
      int row = m0 + wm * 32 + m * 16 + lh * 4 + j;
#pragma unroll
      for (int n = 0; n < 4; ++n)
        C[(size_t)row * G_ + n0 + wn * 64 + n * 16 + ll] = acc[m][n][j] * scale;
    }
}

// ---------------------------------------------------------------------------
// Wave-per-row causal top-8: registers only, no LDS, no barriers.
// Causal load predication: never touch the (cold, garbage) non-causal region.
// Block 0 also writes group_ends.
// ---------------------------------------------------------------------------
__global__ __launch_bounds__(256) void topk_kernel(float* __restrict__ scores,
                                                   int* __restrict__ ends)
{
  if (blockIdx.x == 0) {
    int g = threadIdx.x;
#pragma unroll
    for (int c = 0; c < 4; ++c, g += 256) {
      int e = g * RATIO_ + RATIO_ - 1;
      ends[g] = (e < T_ - 1 ? e : T_ - 1);
    }
  }
  const int r = blockIdx.x * 4 + (threadIdx.x >> 6);
  const int lane = threadIdx.x & 63;
  const int t = r & (T_ - 1);
  const int gmax = (t + 1) >> 2;
  float* row = scores + (size_t)r * G_;
  const int base = lane << 4;
  const float4* p = reinterpret_cast<const float4*>(row + base);
  float4 xv[4];
#pragma unroll
  for (int c = 0; c < 4; ++c) {
    if (base + 4 * c < gmax) xv[c] = p[c];
    else xv[c] = make_float4(-INFINITY, -INFINITY, -INFINITY, -INFINITY);
  }
  float v[16] = {xv[0].x, xv[0].y, xv[0].z, xv[0].w,
                 xv[1].x, xv[1].y, xv[1].z, xv[1].w,
                 xv[2].x, xv[2].y, xv[2].z, xv[2].w,
                 xv[3].x, xv[3].y, xv[3].z, xv[3].w};
#pragma unroll
  for (int j = 0; j < 16; ++j)
    if (base + j >= gmax) v[j] = -INFINITY;
  float lv = v[0]; int li = 0;
#pragma unroll
  for (int j = 1; j < 16; ++j)
    if (v[j] > lv) { lv = v[j]; li = j; }
  unsigned sel = 0;
  const int nsel = gmax < TOPK_ ? gmax : TOPK_;
  for (int it = 0; it < nsel; ++it) {
    float bv = lv; int bi = base + li;
#pragma unroll
    for (int off = 1; off < 64; off <<= 1) {
      float ov = __shfl_xor(bv, off, 64);
      int oi = __shfl_xor(bi, off, 64);
      if (ov > bv || (ov == bv && oi < bi)) { bv = ov; bi = oi; }
    }
    if ((bi >> 4) == lane) {          // winner lane only
      sel |= 1u << (bi & 15);
      v[bi & 15] = -INFINITY;
      lv = v[0]; li = 0;
#pragma unroll
      for (int j = 1; j < 16; ++j)
        if (v[j] > lv) { lv = v[j]; li = j; }
    }
  }
  int4* q = reinterpret_cast<int4*>(row + base);
#pragma unroll
  for (int c = 0; c < 4; ++c)
    q[c] = make_int4((sel >> (4 * c)) & 1, (sel >> (4 * c + 1)) & 1,
                     (sel >> (4 * c + 2)) & 1, (sel >> (4 * c + 3)) & 1);
}

extern "C" void kernel_launch(void* const* d_in, const int* in_sizes, int n_in,
                              void* d_out, int out_size, void* d_ws, size_t ws_size,
                              hipStream_t stream)
{
  const float* x   = (const float*)d_in[0];
  const float* wq  = (const float*)d_in[1];
  const float* wk  = (const float*)d_in[2];
  const float* wg  = (const float*)d_in[3];
  const float* ape = (const float*)d_in[4];

  // ws layout (bf16): wT[3][384][768] | q[16384][384] | keys[4096][384]
  bf16* wT   = (bf16*)d_ws;
  bf16* qb   = wT + 3 * (size_t)HD_ * E_;
  bf16* keys = qb + (size_t)MT_ * HD_;

  cvt_w_t<<<dim3(E_ / 32, HD_ / 32, 3), dim3(256), 0, stream>>>(wq, wk, wg, wT);

  gemm_qkg_mfma<<<dim3(MT_ / 64, HD_ / 128), dim3(256), 0, stream>>>(
      x, wT, wT + (size_t)HD_ * E_, wT + 2 * (size_t)HD_ * E_, ape, qb, keys);

  gemm_score_mfma<<<dim3(T_ / 64, G_ / 128, B_), dim3(256), 0, stream>>>(
      qb, keys, (float*)d_out);

  topk_kernel<<<dim3(MT_ / 4), dim3(256), 0, stream>>>(
      (float*)d_out, (int*)d_out + (size_t)B_ * T_ * G_);
}

// Round 8
// 131.829 us; speedup vs baseline: 1.0745x; 1.0745x over previous
//
#include <hip/hip_runtime.h>
#include <hip/hip_bf16.h>
#include <math.h>

#define B_    4
#define T_    4096
#define E_    768
#define H_    6
#define D_    64
#define HD_   384
#define G_    1024
#define RATIO_ 4
#define TOPK_ 8
#define MT_   (B_*T_)   // 16384 rows total

typedef __attribute__((ext_vector_type(8))) short short8;
typedef __attribute__((ext_vector_type(4))) float f32x4;
typedef __hip_bfloat16 bf16;

// async global->LDS, 16B per lane (dest = linear tid*16; swizzle lives in the
// per-lane GLOBAL source address — rule #21: linear dest + inverse-swz source)
#define GLD16(g, l) __builtin_amdgcn_global_load_lds( \
    (const __attribute__((address_space(1))) void*)(g), \
    (__attribute__((address_space(3))) void*)(l), 16, 0, 0)

static __device__ __forceinline__ unsigned short f2bf(float f) {
  bf16 h = __float2bfloat16(f);
  return __builtin_bit_cast(unsigned short, h);
}

// ---------------------------------------------------------------------------
// x f32 -> bf16 (8 elems/thread)
// ---------------------------------------------------------------------------
__global__ __launch_bounds__(256) void cvt_x_kernel(
    const float* __restrict__ in, bf16* __restrict__ out)
{
  size_t i = (size_t)blockIdx.x * 256 + threadIdx.x;
  const float4* p = reinterpret_cast<const float4*>(in) + i * 2;
  float4 v0 = p[0], v1 = p[1];
  float f[8] = {v0.x, v0.y, v0.z, v0.w, v1.x, v1.y, v1.z, v1.w};
  union { unsigned short u[8]; short8 v; } r;
#pragma unroll
  for (int k = 0; k < 8; ++k) r.u[k] = f2bf(f[k]);
  *reinterpret_cast<short8*>(out + i * 8) = r.v;
}

// ---------------------------------------------------------------------------
// transpose+convert weights: w [768][384] f32 -> wT [384][768] bf16 (x3)
// ---------------------------------------------------------------------------
__global__ __launch_bounds__(256) void cvt_w_t(
    const float* __restrict__ wq, const float* __restrict__ wk,
    const float* __restrict__ wg, bf16* __restrict__ outbase)
{
  const float* src = blockIdx.z == 0 ? wq : (blockIdx.z == 1 ? wk : wg);
  bf16* dst = outbase + (size_t)blockIdx.z * HD_ * E_;
  __shared__ float t[32][33];
  int r = threadIdx.x >> 5, c = threadIdx.x & 31;
  int k0 = blockIdx.x * 32, n0 = blockIdx.y * 32;
#pragma unroll
  for (int i = 0; i < 4; ++i)
    t[r + i * 8][c] = src[(size_t)(k0 + r + i * 8) * HD_ + n0 + c];
  __syncthreads();
#pragma unroll
  for (int i = 0; i < 4; ++i)
    dst[(size_t)(n0 + r + i * 8) * E_ + k0 + c] = __float2bfloat16(t[c][r + i * 8]);
}

// ---------------------------------------------------------------------------
// Fused q/k/gate projection -> q (rmsnormed) + keys (pooled+rmsnormed), bf16.
// 64x128 tile, BK=32. A (x bf16): direct global->reg, prefetched 1 iter ahead.
// B (3 mats): 3-deep LDS ring (72KB, 2 blocks/CU) with COUNTED vmcnt —
// loads stay 2 iterations in flight, never drained to 0 in the main loop (T4).
// Queue math per iter k (issue order: A(k+1) then S(k+2)):
//   outstanding = S(k)6 + A(k)2 + S(k+1)6 + A(k+1)2 + S(k+2)6 = 22
//   need S(k),A(k) retired = oldest 8  ->  vmcnt(14); tail: 8, then 0.
// ---------------------------------------------------------------------------
__global__ __launch_bounds__(256, 2) void gemm_qkg_mfma(
    const bf16* __restrict__ X, const bf16* __restrict__ WqT,
    const bf16* __restrict__ WkT, const bf16* __restrict__ WgT,
    const float* __restrict__ ape, bf16* __restrict__ Q,
    bf16* __restrict__ keys)
{
  // per buf (elems): Q0[0) Q1[2048) K0[4096) K1[6144) G0[8192) G1[10240)
  __shared__ bf16 lds[3][12288];   // 24KB/buf, 72KB total
  const int tid = threadIdx.x;
  const int lane = tid & 63, wv = tid >> 6;
  const int wm = wv >> 1, wn = wv & 1;
  const int ll = lane & 15, lh = lane >> 4;
  const int m0 = blockIdx.x * 64, n0 = blockIdx.y * 128;
  const int srow = tid >> 2;
  const int scol = (((tid & 3) ^ ((tid >> 3) & 3)) << 3);  // swizzled source slot
  const bf16* pQ0 = WqT + (size_t)(n0 + srow) * E_ + scol;
  const bf16* pQ1 = WqT + (size_t)(n0 + 64 + srow) * E_ + scol;
  const bf16* pK0 = WkT + (size_t)(n0 + srow) * E_ + scol;
  const bf16* pK1 = WkT + (size_t)(n0 + 64 + srow) * E_ + scol;
  const bf16* pG0 = WgT + (size_t)(n0 + srow) * E_ + scol;
  const bf16* pG1 = WgT + (size_t)(n0 + 64 + srow) * E_ + scol;
  // A direct-from-global (bf16): 16 rows x 64B cache lines per load
  const bf16* pA0 = X + (size_t)(m0 + wm * 32 + ll) * E_ + lh * 8;
  const bf16* pA1 = pA0 + (size_t)16 * E_;

#define QKG_STAGE(b, k0) do { \
    char* base_ = (char*)&lds[b][0] + tid * 16; \
    GLD16(pQ0 + (k0), base_); \
    GLD16(pQ1 + (k0), base_ + 4096); \
    GLD16(pK0 + (k0), base_ + 8192); \
    GLD16(pK1 + (k0), base_ + 12288); \
    GLD16(pG0 + (k0), base_ + 16384); \
    GLD16(pG1 + (k0), base_ + 20480); \
  } while (0)

  f32x4 accQ[2][4], accK[2][4], accG[2][4];
#pragma unroll
  for (int m = 0; m < 2; ++m)
#pragma unroll
    for (int n = 0; n < 4; ++n) {
      accQ[m][n] = (f32x4){0.f, 0.f, 0.f, 0.f};
      accK[m][n] = (f32x4){0.f, 0.f, 0.f, 0.f};
      accG[m][n] = (f32x4){0.f, 0.f, 0.f, 0.f};
    }
  const int asw = (lh ^ ((ll >> 1) & 3)) << 3;  // swizzled read slot (elems)

  // prologue: A(0), S(0), S(1)  (order matters for the vmcnt math)
  short8 curA0 = *reinterpret_cast<const short8*>(pA0);
  short8 curA1 = *reinterpret_cast<const short8*>(pA1);
  QKG_STAGE(0, 0);
  QKG_STAGE(1, 32);
  short8 nxtA0 = curA0, nxtA1 = curA1;

#pragma unroll
  for (int k = 0; k < 24; ++k) {
    const int k0 = k * 32;
    if (k < 23) {  // A(k+1)
      nxtA0 = *reinterpret_cast<const short8*>(pA0 + k0 + 32);
      nxtA1 = *reinterpret_cast<const short8*>(pA1 + k0 + 32);
    }
    if (k < 22) QKG_STAGE((k + 2) % 3, k0 + 64);   // S(k+2)
    if (k < 22)      asm volatile("s_waitcnt vmcnt(14)" ::: "memory");
    else if (k == 22) asm volatile("s_waitcnt vmcnt(8)"  ::: "memory");
    else              asm volatile("s_waitcnt vmcnt(0)"  ::: "memory");
    __builtin_amdgcn_s_barrier();          // buf[k%3] staged by ALL waves
    __builtin_amdgcn_sched_barrier(0);     // pin: no ds_read hoisted above
    const bf16* Lb = &lds[k % 3][0];
    short8 bq[4], bk[4], bg[4];
#pragma unroll
    for (int n = 0; n < 4; ++n) {
      int R = (wn * 64 + n * 16 + ll) * 32 + asw;
      bq[n] = *reinterpret_cast<const short8*>(&Lb[R]);
      bk[n] = *reinterpret_cast<const short8*>(&Lb[4096 + R]);
      bg[n] = *reinterpret_cast<const short8*>(&Lb[8192 + R]);
    }
    asm volatile("s_waitcnt lgkmcnt(0)" ::: "memory");  // my reads landed
    __builtin_amdgcn_s_barrier();          // all waves done reading buf[k%3]
#pragma unroll
    for (int m = 0; m < 2; ++m) {
      short8 am = m == 0 ? curA0 : curA1;
#pragma unroll
      for (int n = 0; n < 4; ++n) {
        accQ[m][n] = __builtin_amdgcn_mfma_f32_16x16x32_bf16(am, bq[n], accQ[m][n], 0, 0, 0);
        accK[m][n] = __builtin_amdgcn_mfma_f32_16x16x32_bf16(am, bk[n], accK[m][n], 0, 0, 0);
        accG[m][n] = __builtin_amdgcn_mfma_f32_16x16x32_bf16(am, bg[n], accG[m][n], 0, 0, 0);
      }
    }
    curA0 = nxtA0; curA1 = nxtA1;
  }
#undef QKG_STAGE

  // ---- q epilogue: per-(row,head) rmsnorm (wave's 64 cols == one head) ----
#pragma unroll
  for (int m = 0; m < 2; ++m)
#pragma unroll
    for (int j = 0; j < 4; ++j) {
      float ss = 0.f;
#pragma unroll
      for (int n = 0; n < 4; ++n) ss += accQ[m][n][j] * accQ[m][n][j];
      ss += __shfl_xor(ss, 1, 64); ss += __shfl_xor(ss, 2, 64);
      ss += __shfl_xor(ss, 4, 64); ss += __shfl_xor(ss, 8, 64);
      float scl = rsqrtf(ss * (1.0f / D_) + 1e-6f);
      int row = m0 + wm * 32 + m * 16 + lh * 4 + j;
#pragma unroll
      for (int n = 0; n < 4; ++n)
        Q[(size_t)row * HD_ + n0 + wn * 64 + n * 16 + ll] =
            __float2bfloat16(accQ[m][n][j] * scl);
    }

  // ---- keys epilogue: lane-local softmax over 4 group rows + rmsnorm ----
  float apev[4][4];
#pragma unroll
  for (int n = 0; n < 4; ++n) {
    int col = n0 + wn * 64 + n * 16 + ll;
#pragma unroll
    for (int j = 0; j < 4; ++j) apev[n][j] = ape[j * HD_ + col];
  }
#pragma unroll
  for (int m = 0; m < 2; ++m) {
    float pooled[4];
#pragma unroll
    for (int n = 0; n < 4; ++n) {
      float g0 = accG[m][n][0] + apev[n][0], g1 = accG[m][n][1] + apev[n][1];
      float g2 = accG[m][n][2] + apev[n][2], g3 = accG[m][n][3] + apev[n][3];
      float mx = fmaxf(fmaxf(g0, g1), fmaxf(g2, g3));
      float e0 = expf(g0 - mx), e1 = expf(g1 - mx);
      float e2 = expf(g2 - mx), e3 = expf(g3 - mx);
      float inv = 1.0f / (e0 + e1 + e2 + e3);
      pooled[n] = (accK[m][n][0] * e0 + accK[m][n][1] * e1 +
                   accK[m][n][2] * e2 + accK[m][n][3] * e3) * inv;
    }
    float ss = pooled[0] * pooled[0] + pooled[1] * pooled[1] +
               pooled[2] * pooled[2] + pooled[3] * pooled[3];
    ss += __shfl_xor(ss, 1, 64); ss += __shfl_xor(ss, 2, 64);
    ss += __shfl_xor(ss, 4, 64); ss += __shfl_xor(ss, 8, 64);
    float scl = rsqrtf(ss * (1.0f / D_) + 1e-6f);
    int prow = (m0 >> 2) + wm * 8 + m * 4 + lh;
#pragma unroll
    for (int n = 0; n < 4; ++n)
      keys[(size_t)prow * HD_ + n0 + wn * 64 + n * 16 + ll] =
          __float2bfloat16(pooled[n] * scl);
  }
}

// ---------------------------------------------------------------------------
// Batched score GEMM: scores[z] = q[z] @ keys[z]^T * (D^-0.5/H).
// A (q) direct global->reg; B (keys) dbuf LDS 16KB; causal dead-tile skip.
// ---------------------------------------------------------------------------
__global__ __launch_bounds__(256, 4) void gemm_score_mfma(
    const bf16* __restrict__ Qall, const bf16* __restrict__ Kall,
    float* __restrict__ Call)
{
  const int m0 = blockIdx.x * 64, n0 = blockIdx.y * 128;
  if (4 * n0 >= m0 + 64) return;   // all cols >= gmax for every row in tile
  __shared__ bf16 lds[2][4096];    // B only: 8KB/buf
  const bf16* Qb = Qall + (size_t)blockIdx.z * T_ * HD_;
  const bf16* Kb = Kall + (size_t)blockIdx.z * G_ * HD_;
  float* C = Call + (size_t)blockIdx.z * T_ * G_;
  const int tid = threadIdx.x;
  const int lane = tid & 63, wv = tid >> 6;
  const int wm = wv >> 1, wn = wv & 1;
  const int ll = lane & 15, lh = lane >> 4;
  const int srow = tid >> 2;
  const int scol = (((tid & 3) ^ ((tid >> 3) & 3)) << 3);
  const bf16* pB0 = Kb + (size_t)(n0 + srow) * HD_ + scol;
  const bf16* pB1 = Kb + (size_t)(n0 + 64 + srow) * HD_ + scol;
  const bf16* pA0 = Qb + (size_t)(m0 + wm * 32 + ll) * HD_ + lh * 8;
  const bf16* pA1 = pA0 + (size_t)16 * HD_;

#define S_STAGE(b, k0) do { \
    char* base_ = (char*)&lds[b][0] + tid * 16; \
    GLD16(pB0 + (k0), base_); \
    GLD16(pB1 + (k0), base_ + 4096); \
  } while (0)

  f32x4 acc[2][4];
#pragma unroll
  for (int m = 0; m < 2; ++m)
#pragma unroll
    for (int n = 0; n < 4; ++n) acc[m][n] = (f32x4){0.f, 0.f, 0.f, 0.f};
  const int asw = (lh ^ ((ll >> 1) & 3)) << 3;

  S_STAGE(0, 0);
  __syncthreads();
  for (int k0 = 0; k0 < HD_; k0 += 32) {
    const int cur = (k0 >> 5) & 1;
    if (k0 + 32 < HD_) S_STAGE(cur ^ 1, k0 + 32);
    short8 a[2], b[4];
    a[0] = *reinterpret_cast<const short8*>(pA0 + k0);
    a[1] = *reinterpret_cast<const short8*>(pA1 + k0);
    const bf16* Lb = &lds[cur][0];
#pragma unroll
    for (int n = 0; n < 4; ++n)
      b[n] = *reinterpret_cast<const short8*>(&Lb[(wn * 64 + n * 16 + ll) * 32 + asw]);
#pragma unroll
    for (int m = 0; m < 2; ++m)
#pragma unroll
      for (int n = 0; n < 4; ++n)
        acc[m][n] = __builtin_amdgcn_mfma_f32_16x16x32_bf16(a[m], b[n], acc[m][n], 0, 0, 0);
    __syncthreads();
  }
#undef S_STAGE
  const float scale = 0.125f / 6.0f;
#pragma unroll
  for (int m = 0; m < 2; ++m)
#pragma unroll
    for (int j = 0; j < 4; ++j) {
      int row = m0 + wm * 32 + m * 16 + lh * 4 + j;
#pragma unroll
      for (int n = 0; n < 4; ++n)
        C[(size_t)row * G_ + n0 + wn * 64 + n * 16 + ll] = acc[m][n][j] * scale;
    }
}

// ---------------------------------------------------------------------------
// Wave-per-row causal top-8: registers only, no LDS, no barriers.
// Causal load predication: never touch the (cold, garbage) non-causal region.
// Block 0 also writes group_ends.
// ---------------------------------------------------------------------------
__global__ __launch_bounds__(256) void topk_kernel(float* __restrict__ scores,
                                                   int* __restrict__ ends)
{
  if (blockIdx.x == 0) {
    int g = threadIdx.x;
#pragma unroll
    for (int c = 0; c < 4; ++c, g += 256) {
      int e = g * RATIO_ + RATIO_ - 1;
      ends[g] = (e < T_ - 1 ? e : T_ - 1);
    }
  }
  const int r = blockIdx.x * 4 + (threadIdx.x >> 6);
  const int lane = threadIdx.x & 63;
  const int t = r & (T_ - 1);
  const int gmax = (t + 1) >> 2;
  float* row = scores + (size_t)r * G_;
  const int base = lane << 4;
  const float4* p = reinterpret_cast<const float4*>(row + base);
  float4 xv[4];
#pragma unroll
  for (int c = 0; c < 4; ++c) {
    if (base + 4 * c < gmax) xv[c] = p[c];
    else xv[c] = make_float4(-INFINITY, -INFINITY, -INFINITY, -INFINITY);
  }
  float v[16] = {xv[0].x, xv[0].y, xv[0].z, xv[0].w,
                 xv[1].x, xv[1].y, xv[1].z, xv[1].w,
                 xv[2].x, xv[2].y, xv[2].z, xv[2].w,
                 xv[3].x, xv[3].y, xv[3].z, xv[3].w};
#pragma unroll
  for (int j = 0; j < 16; ++j)
    if (base + j >= gmax) v[j] = -INFINITY;
  float lv = v[0]; int li = 0;
#pragma unroll
  for (int j = 1; j < 16; ++j)
    if (v[j] > lv) { lv = v[j]; li = j; }
  unsigned sel = 0;
  const int nsel = gmax < TOPK_ ? gmax : TOPK_;
  for (int it = 0; it < nsel; ++it) {
    float bv = lv; int bi = base + li;
#pragma unroll
    for (int off = 1; off < 64; off <<= 1) {
      float ov = __shfl_xor(bv, off, 64);
      int oi = __shfl_xor(bi, off, 64);
      if (ov > bv || (ov == bv && oi < bi)) { bv = ov; bi = oi; }
    }
    if ((bi >> 4) == lane) {          // winner lane only
      sel |= 1u << (bi & 15);
      v[bi & 15] = -INFINITY;
      lv = v[0]; li = 0;
#pragma unroll
      for (int j = 1; j < 16; ++j)
        if (v[j] > lv) { lv = v[j]; li = j; }
    }
  }
  int4* q = reinterpret_cast<int4*>(row + base);
#pragma unroll
  for (int c = 0; c < 4; ++c)
    q[c] = make_int4((sel >> (4 * c)) & 1, (sel >> (4 * c + 1)) & 1,
                     (sel >> (4 * c + 2)) & 1, (sel >> (4 * c + 3)) & 1);
}

extern "C" void kernel_launch(void* const* d_in, const int* in_sizes, int n_in,
                              void* d_out, int out_size, void* d_ws, size_t ws_size,
                              hipStream_t stream)
{
  const float* x   = (const float*)d_in[0];
  const float* wq  = (const float*)d_in[1];
  const float* wk  = (const float*)d_in[2];
  const float* wg  = (const float*)d_in[3];
  const float* ape = (const float*)d_in[4];

  // ws layout (bf16): wT[3][384][768] | q[16384][384] | keys[4096][384]
  bf16* wT   = (bf16*)d_ws;
  bf16* qb   = wT + 3 * (size_t)HD_ * E_;
  bf16* keys = qb + (size_t)MT_ * HD_;

  // x_bf16 staged in d_out (dead before scores overwrite it)
  bf16* xb = (bf16*)d_out;

  cvt_x_kernel<<<dim3(MT_ * E_ / 8 / 256), dim3(256), 0, stream>>>(x, xb);
  cvt_w_t<<<dim3(E_ / 32, HD_ / 32, 3), dim3(256), 0, stream>>>(wq, wk, wg, wT);

  gemm_qkg_mfma<<<dim3(MT_ / 64, HD_ / 128), dim3(256), 0, stream>>>(
      xb, wT, wT + (size_t)HD_ * E_, wT + 2 * (size_t)HD_ * E_, ape, qb, keys);

  gemm_score_mfma<<<dim3(T_ / 64, G_ / 128, B_), dim3(256), 0, stream>>>(
      qb, keys, (float*)d_out);

  topk_kernel<<<dim3(MT_ / 4), dim3(256), 0, stream>>>(
      (float*)d_out, (int*)d_out + (size_t)B_ * T_ * G_);
}

// Round 9
// 124.072 us; speedup vs baseline: 1.1417x; 1.0625x over previous
//
#include <hip/hip_runtime.h>
#include <hip/hip_bf16.h>
#include <math.h>

#define B_    4
#define T_    4096
#define E_    768
#define H_    6
#define D_    64
#define HD_   384
#define G_    1024
#define RATIO_ 4
#define TOPK_ 8
#define MT_   (B_*T_)   // 16384 rows total
#define NS_   1152      // stacked N: [384 q][768 kg-interleaved]

typedef __attribute__((ext_vector_type(8))) short short8;
typedef __attribute__((ext_vector_type(4))) float f32x4;
typedef __hip_bfloat16 bf16;

// async global->LDS, 16B per lane (dest = linear tid*16; swizzle lives in the
// per-lane GLOBAL source address — rule #21: linear dest + inverse-swz source)
#define GLD16(g, l) __builtin_amdgcn_global_load_lds( \
    (const __attribute__((address_space(1))) void*)(g), \
    (__attribute__((address_space(3))) void*)(l), 16, 0, 0)

static __device__ __forceinline__ unsigned short f2bf(float f) {
  bf16 h = __float2bfloat16(f);
  return __builtin_bit_cast(unsigned short, h);
}

// ---------------------------------------------------------------------------
// x f32 -> bf16 (8 elems/thread)
// ---------------------------------------------------------------------------
__global__ __launch_bounds__(256) void cvt_x_kernel(
    const float* __restrict__ in, bf16* __restrict__ out)
{
  size_t i = (size_t)blockIdx.x * 256 + threadIdx.x;
  const float4* p = reinterpret_cast<const float4*>(in) + i * 2;
  float4 v0 = p[0], v1 = p[1];
  float f[8] = {v0.x, v0.y, v0.z, v0.w, v1.x, v1.y, v1.z, v1.w};
  union { unsigned short u[8]; short8 v; } r;
#pragma unroll
  for (int k = 0; k < 8; ++k) r.u[k] = f2bf(f[k]);
  *reinterpret_cast<short8*>(out + i * 8) = r.v;
}

// ---------------------------------------------------------------------------
// transpose+convert+STACK weights into Ws [1152][768] bf16:
//   q col c    -> row c
//   k col c    -> row 384 + (c>>4)*32 + (c&15)        (16-col slots, even)
//   g col c    -> row 384 + (c>>4)*32 + 16 + (c&15)   (odd slots)
// so a 128-col kg tile holds alternating k/g frags for the SAME head dims.
// ---------------------------------------------------------------------------
__global__ __launch_bounds__(256) void cvt_w_t(
    const float* __restrict__ wq, const float* __restrict__ wk,
    const float* __restrict__ wg, bf16* __restrict__ outbase)
{
  const int z = blockIdx.z;
  const float* src = z == 0 ? wq : (z == 1 ? wk : wg);
  __shared__ float t[32][33];
  int r = threadIdx.x >> 5, c = threadIdx.x & 31;
  int k0 = blockIdx.x * 32, n0 = blockIdx.y * 32;
#pragma unroll
  for (int i = 0; i < 4; ++i)
    t[r + i * 8][c] = src[(size_t)(k0 + r + i * 8) * HD_ + n0 + c];
  __syncthreads();
#pragma unroll
  for (int i = 0; i < 4; ++i) {
    int cc = n0 + r + i * 8;
    int ro = (z == 0) ? cc : 384 + ((cc >> 4) << 5) + ((z - 1) << 4) + (cc & 15);
    outbase[(size_t)ro * E_ + k0 + c] = __float2bfloat16(t[c][r + i * 8]);
  }
}

// ---------------------------------------------------------------------------
// ONE fused projection GEMM: [MT x 768] @ Ws^T -> q (rmsnormed) + keys
// (softmax-pooled + rmsnormed). 128x128 tile, 4 waves stacked in M
// (wave = 32M x 128N, acc 2x8). A: direct global->reg, prefetched 1 iter.
// B: 3-deep LDS ring (24KB) + counted vmcnt (T4). Epilogue by panel type.
// ---------------------------------------------------------------------------
__global__ __launch_bounds__(256, 3) void gemm_qkg_mfma(
    const bf16* __restrict__ X, const bf16* __restrict__ Ws,
    const float* __restrict__ ape, bf16* __restrict__ Q,
    bf16* __restrict__ keys)
{
  __shared__ bf16 lds[3][4096];   // [128 rows][32 k] per buf = 8KB
  const int tid = threadIdx.x;
  const int lane = tid & 63, wv = tid >> 6;
  const int ll = lane & 15, lh = lane >> 4;
  const int m0 = blockIdx.x * 128, n0 = blockIdx.y * 128;
  const int srow = tid >> 2;
  const int scol = (((tid & 3) ^ ((tid >> 3) & 3)) << 3);  // swizzled src slot
  const bf16* pB0 = Ws + (size_t)(n0 + srow) * E_ + scol;
  const bf16* pB1 = Ws + (size_t)(n0 + 64 + srow) * E_ + scol;
  // A: per-wave-private 32 rows, direct from global (16 rows x 64B lines)
  const bf16* pA0 = X + (size_t)(m0 + wv * 32 + ll) * E_ + lh * 8;
  const bf16* pA1 = pA0 + (size_t)16 * E_;

#define STAGE(b, k0) do { \
    char* base_ = (char*)&lds[b][0] + tid * 16; \
    GLD16(pB0 + (k0), base_); \
    GLD16(pB1 + (k0), base_ + 4096); \
  } while (0)

  f32x4 acc[2][8];
#pragma unroll
  for (int m = 0; m < 2; ++m)
#pragma unroll
    for (int n = 0; n < 8; ++n) acc[m][n] = (f32x4){0.f, 0.f, 0.f, 0.f};
  const int asw = (lh ^ ((ll >> 1) & 3)) << 3;  // swizzled read slot (elems)

  // prologue: A(0), S(0), S(1)
  short8 curA0 = *reinterpret_cast<const short8*>(pA0);
  short8 curA1 = *reinterpret_cast<const short8*>(pA1);
  STAGE(0, 0);
  STAGE(1, 32);
  short8 nxtA0 = curA0, nxtA1 = curA1;

#pragma unroll
  for (int k = 0; k < 24; ++k) {
    const int k0 = k * 32;
    if (k < 23) {  // A(k+1)
      nxtA0 = *reinterpret_cast<const short8*>(pA0 + k0 + 32);
      nxtA1 = *reinterpret_cast<const short8*>(pA1 + k0 + 32);
    }
    if (k < 22) STAGE((k + 2) % 3, k0 + 64);   // S(k+2)
    // retire S(k)+A(k) = oldest 4; queue = {S(k)2,A(k)2,S(k+1)2,A(k+1)2,S(k+2)2}
    if (k < 22)       asm volatile("s_waitcnt vmcnt(6)" ::: "memory");
    else if (k == 22) asm volatile("s_waitcnt vmcnt(4)" ::: "memory");
    else              asm volatile("s_waitcnt vmcnt(0)" ::: "memory");
    __builtin_amdgcn_s_barrier();          // buf[k%3] staged by ALL waves
    __builtin_amdgcn_sched_barrier(0);     // pin: no ds_read hoisted above
    const bf16* Lb = &lds[k % 3][0];
    short8 b[8];
#pragma unroll
    for (int n = 0; n < 8; ++n)
      b[n] = *reinterpret_cast<const short8*>(&Lb[(n * 16 + ll) * 32 + asw]);
    asm volatile("s_waitcnt lgkmcnt(0)" ::: "memory");  // my reads landed
    __builtin_amdgcn_sched_barrier(0);
    __builtin_amdgcn_s_barrier();          // all waves done reading buf[k%3]
#pragma unroll
    for (int m = 0; m < 2; ++m) {
      short8 am = (m == 0) ? curA0 : curA1;
#pragma unroll
      for (int n = 0; n < 8; ++n)
        acc[m][n] = __builtin_amdgcn_mfma_f32_16x16x32_bf16(am, b[n], acc[m][n], 0, 0, 0);
    }
    curA0 = nxtA0; curA1 = nxtA1;
  }
#undef STAGE

  if (blockIdx.y < 3) {
    // ---- q epilogue: 2 heads per wave; rmsnorm over each 64-col head ----
#pragma unroll
    for (int m = 0; m < 2; ++m)
#pragma unroll
      for (int j = 0; j < 4; ++j) {
        int row = m0 + wv * 32 + m * 16 + lh * 4 + j;
#pragma unroll
        for (int h = 0; h < 2; ++h) {
          float ss = 0.f;
#pragma unroll
          for (int n = 4 * h; n < 4 * h + 4; ++n) ss += acc[m][n][j] * acc[m][n][j];
          ss += __shfl_xor(ss, 1, 64); ss += __shfl_xor(ss, 2, 64);
          ss += __shfl_xor(ss, 4, 64); ss += __shfl_xor(ss, 8, 64);
          float scl = rsqrtf(ss * (1.0f / D_) + 1e-6f);
#pragma unroll
          for (int n = 4 * h; n < 4 * h + 4; ++n)
            Q[(size_t)row * HD_ + n0 + n * 16 + ll] =
                __float2bfloat16(acc[m][n][j] * scl);
        }
      }
  } else {
    // ---- kg epilogue: frags alternate k,g; pool 4 pairs = full head ----
    const int hcb = (n0 - 384) >> 1;   // head-col base (one full head/block-col)
    float apev[4][4];
#pragma unroll
    for (int p = 0; p < 4; ++p) {
      int hc = hcb + p * 16 + ll;
#pragma unroll
      for (int j = 0; j < 4; ++j) apev[p][j] = ape[j * HD_ + hc];
    }
#pragma unroll
    for (int m = 0; m < 2; ++m) {
      float pooled[4];
#pragma unroll
      for (int p = 0; p < 4; ++p) {
        float g0 = acc[m][2 * p + 1][0] + apev[p][0];
        float g1 = acc[m][2 * p + 1][1] + apev[p][1];
        float g2 = acc[m][2 * p + 1][2] + apev[p][2];
        float g3 = acc[m][2 * p + 1][3] + apev[p][3];
        float mx = fmaxf(fmaxf(g0, g1), fmaxf(g2, g3));
        float e0 = expf(g0 - mx), e1 = expf(g1 - mx);
        float e2 = expf(g2 - mx), e3 = expf(g3 - mx);
        float inv = 1.0f / (e0 + e1 + e2 + e3);
        pooled[p] = (acc[m][2 * p][0] * e0 + acc[m][2 * p][1] * e1 +
                     acc[m][2 * p][2] * e2 + acc[m][2 * p][3] * e3) * inv;
      }
      float ss = pooled[0] * pooled[0] + pooled[1] * pooled[1] +
                 pooled[2] * pooled[2] + pooled[3] * pooled[3];
      ss += __shfl_xor(ss, 1, 64); ss += __shfl_xor(ss, 2, 64);
      ss += __shfl_xor(ss, 4, 64); ss += __shfl_xor(ss, 8, 64);
      float scl = rsqrtf(ss * (1.0f / D_) + 1e-6f);
      int prow = (m0 >> 2) + wv * 8 + m * 4 + lh;
#pragma unroll
      for (int p = 0; p < 4; ++p)
        keys[(size_t)prow * HD_ + hcb + p * 16 + ll] =
            __float2bfloat16(pooled[p] * scl);
    }
  }
}

// ---------------------------------------------------------------------------
// Batched score GEMM: scores[z] = q[z] @ keys[z]^T * (D^-0.5/H).
// A (q) direct global->reg; B (keys) dbuf LDS 16KB; causal dead-tile skip.
// ---------------------------------------------------------------------------
__global__ __launch_bounds__(256, 4) void gemm_score_mfma(
    const bf16* __restrict__ Qall, const bf16* __restrict__ Kall,
    float* __restrict__ Call)
{
  const int m0 = blockIdx.x * 64, n0 = blockIdx.y * 128;
  if (4 * n0 >= m0 + 64) return;   // all cols >= gmax for every row in tile
  __shared__ bf16 lds[2][4096];    // B only: 8KB/buf
  const bf16* Qb = Qall + (size_t)blockIdx.z * T_ * HD_;
  const bf16* Kb = Kall + (size_t)blockIdx.z * G_ * HD_;
  float* C = Call + (size_t)blockIdx.z * T_ * G_;
  const int tid = threadIdx.x;
  const int lane = tid & 63, wv = tid >> 6;
  const int wm = wv >> 1, wn = wv & 1;
  const int ll = lane & 15, lh = lane >> 4;
  const int srow = tid >> 2;
  const int scol = (((tid & 3) ^ ((tid >> 3) & 3)) << 3);
  const bf16* pB0 = Kb + (size_t)(n0 + srow) * HD_ + scol;
  const bf16* pB1 = Kb + (size_t)(n0 + 64 + srow) * HD_ + scol;
  const bf16* pA0 = Qb + (size_t)(m0 + wm * 32 + ll) * HD_ + lh * 8;
  const bf16* pA1 = pA0 + (size_t)16 * HD_;

#define S_STAGE(b, k0) do { \
    char* base_ = (char*)&lds[b][0] + tid * 16; \
    GLD16(pB0 + (k0), base_); \
    GLD16(pB1 + (k0), base_ + 4096); \
  } while (0)

  f32x4 acc[2][4];
#pragma unroll
  for (int m = 0; m < 2; ++m)
#pragma unroll
    for (int n = 0; n < 4; ++n) acc[m][n] = (f32x4){0.f, 0.f, 0.f, 0.f};
  const int asw = (lh ^ ((ll >> 1) & 3)) << 3;

  S_STAGE(0, 0);
  __syncthreads();
  for (int k0 = 0; k0 < HD_; k0 += 32) {
    const int cur = (k0 >> 5) & 1;
    if (k0 + 32 < HD_) S_STAGE(cur ^ 1, k0 + 32);
    short8 a[2], b[4];
    a[0] = *reinterpret_cast<const short8*>(pA0 + k0);
    a[1] = *reinterpret_cast<const short8*>(pA1 + k0);
    const bf16* Lb = &lds[cur][0];
#pragma unroll
    for (int n = 0; n < 4; ++n)
      b[n] = *reinterpret_cast<const short8*>(&Lb[(wn * 64 + n * 16 + ll) * 32 + asw]);
#pragma unroll
    for (int m = 0; m < 2; ++m)
#pragma unroll
      for (int n = 0; n < 4; ++n)
        acc[m][n] = __builtin_amdgcn_mfma_f32_16x16x32_bf16(a[m], b[n], acc[m][n], 0, 0, 0);
    __syncthreads();
  }
#undef S_STAGE
  const float scale = 0.125f / 6.0f;
#pragma unroll
  for (int m = 0; m < 2; ++m)
#pragma unroll
    for (int j = 0; j < 4; ++j) {
      int row = m0 + wm * 32 + m * 16 + lh * 4 + j;
#pragma unroll
      for (int n = 0; n < 4; ++n)
        C[(size_t)row * G_ + n0 + wn * 64 + n * 16 + ll] = acc[m][n][j] * scale;
    }
}

// ---------------------------------------------------------------------------
// Wave-per-row causal top-8: registers only, no LDS, no barriers.
// Causal load predication: never touch the (cold, garbage) non-causal region.
// Block 0 also writes group_ends.
// ---------------------------------------------------------------------------
__global__ __launch_bounds__(256) void topk_kernel(float* __restrict__ scores,
                                                   int* __restrict__ ends)
{
  if (blockIdx.x == 0) {
    int g = threadIdx.x;
#pragma unroll
    for (int c = 0; c < 4; ++c, g += 256) {
      int e = g * RATIO_ + RATIO_ - 1;
      ends[g] = (e < T_ - 1 ? e : T_ - 1);
    }
  }
  const int r = blockIdx.x * 4 + (threadIdx.x >> 6);
  const int lane = threadIdx.x & 63;
  const int t = r & (T_ - 1);
  const int gmax = (t + 1) >> 2;
  float* row = scores + (size_t)r * G_;
  const int base = lane << 4;
  const float4* p = reinterpret_cast<const float4*>(row + base);
  float4 xv[4];
#pragma unroll
  for (int c = 0; c < 4; ++c) {
    if (base + 4 * c < gmax) xv[c] = p[c];
    else xv[c] = make_float4(-INFINITY, -INFINITY, -INFINITY, -INFINITY);
  }
  float v[16] = {xv[0].x, xv[0].y, xv[0].z, xv[0].w,
                 xv[1].x, xv[1].y, xv[1].z, xv[1].w,
                 xv[2].x, xv[2].y, xv[2].z, xv[2].w,
                 xv[3].x, xv[3].y, xv[3].z, xv[3].w};
#pragma unroll
  for (int j = 0; j < 16; ++j)
    if (base + j >= gmax) v[j] = -INFINITY;
  float lv = v[0]; int li = 0;
#pragma unroll
  for (int j = 1; j < 16; ++j)
    if (v[j] > lv) { lv = v[j]; li = j; }
  unsigned sel = 0;
  const int nsel = gmax < TOPK_ ? gmax : TOPK_;
  for (int it = 0; it < nsel; ++it) {
    float bv = lv; int bi = base + li;
#pragma unroll
    for (int off = 1; off < 64; off <<= 1) {
      float ov = __shfl_xor(bv, off, 64);
      int oi = __shfl_xor(bi, off, 64);
      if (ov > bv || (ov == bv && oi < bi)) { bv = ov; bi = oi; }
    }
    if ((bi >> 4) == lane) {          // winner lane only
      sel |= 1u << (bi & 15);
      v[bi & 15] = -INFINITY;
      lv = v[0]; li = 0;
#pragma unroll
      for (int j = 1; j < 16; ++j)
        if (v[j] > lv) { lv = v[j]; li = j; }
    }
  }
  int4* q = reinterpret_cast<int4*>(row + base);
#pragma unroll
  for (int c = 0; c < 4; ++c)
    q[c] = make_int4((sel >> (4 * c)) & 1, (sel >> (4 * c + 1)) & 1,
                     (sel >> (4 * c + 2)) & 1, (sel >> (4 * c + 3)) & 1);
}

extern "C" void kernel_launch(void* const* d_in, const int* in_sizes, int n_in,
                              void* d_out, int out_size, void* d_ws, size_t ws_size,
                              hipStream_t stream)
{
  const float* x   = (const float*)d_in[0];
  const float* wq  = (const float*)d_in[1];
  const float* wk  = (const float*)d_in[2];
  const float* wg  = (const float*)d_in[3];
  const float* ape = (const float*)d_in[4];

  // ws layout (bf16): Ws[1152][768] | q[16384][384] | keys[4096][384]
  bf16* Ws   = (bf16*)d_ws;
  bf16* qb   = Ws + (size_t)NS_ * E_;
  bf16* keys = qb + (size_t)MT_ * HD_;

  // x_bf16 staged in d_out (dead before scores overwrite it)
  bf16* xb = (bf16*)d_out;

  cvt_x_kernel<<<dim3(MT_ * E_ / 8 / 256), dim3(256), 0, stream>>>(x, xb);
  cvt_w_t<<<dim3(E_ / 32, HD_ / 32, 3), dim3(256), 0, stream>>>(wq, wk, wg, Ws);

  gemm_qkg_mfma<<<dim3(MT_ / 128, NS_ / 128), dim3(256), 0, stream>>>(
      xb, Ws, ape, qb, keys);

  gemm_score_mfma<<<dim3(T_ / 64, G_ / 128, B_), dim3(256), 0, stream>>>(
      qb, keys, (float*)d_out);

  topk_kernel<<<dim3(MT_ / 4), dim3(256), 0, stream>>>(
      (float*)d_out, (int*)d_out + (size_t)B_ * T_ * G_);
}